// Round 1
// 153.049 us; speedup vs baseline: 1.0024x; 1.0024x over previous
//
#include <hip/hip_runtime.h>
#include <hip/hip_bf16.h>

// ---------------------------------------------------------------------------
// MultiHeadAttention forward on MI355X (gfx950). B=2,S=2048,D=768,H=12,Dh=64.
// Masks scale by +1e-9 (numeric no-op) -> full non-causal softmax; dropped.
//
// Round 6 = round 5 + attention 2-phase pipeline:
//  * k_attn: 64-key tiles, double-buffered K/V LDS (32 KB total, occupancy
//    unchanged), T3-minimum schedule (issue next tile's global_load_lds
//    BEFORE computing current tile; ONE __syncthreads per tile) so staging
//    latency hides under QK^T/exp/PV. s_setprio(1) around MFMA cluster (T5).
//  * QKV GEMM 128x96 tiles -> (32,24)=768 blocks = 3/CU exact balance.
//  * Proj GEMM 64x64 tiles -> (64,12)=768 blocks = 3/CU.
//  * Prep (f32->bf16 cast + 2 weight transposes) fused into one launch.
// ---------------------------------------------------------------------------

typedef __attribute__((ext_vector_type(8))) short short8;
typedef __attribute__((ext_vector_type(4))) float float4v;
typedef __attribute__((ext_vector_type(8))) _Float16 half8;
typedef __attribute__((ext_vector_type(4))) _Float16 half4;
typedef __attribute__((ext_vector_type(4))) unsigned short ushort4v;

__device__ __forceinline__ void async_copy16(const void* g, void* l) {
  __builtin_amdgcn_global_load_lds(
      (const __attribute__((address_space(1))) void*)g,
      (__attribute__((address_space(3))) void*)l, 16, 0, 0);
}

__device__ __forceinline__ float fast_exp2(float x) {
#if __has_builtin(__builtin_amdgcn_exp2f)
  return __builtin_amdgcn_exp2f(x);
#else
  return exp2f(x);
#endif
}

__device__ __forceinline__ unsigned short f2bf(float v) {
  __hip_bfloat16 h = __float2bfloat16(v);
  unsigned short u;
  __builtin_memcpy(&u, &h, 2);
  return u;
}

#define LOG2E_8 0.18033688011112042f  // log2(e)/8, folded into Q

// ---- fused prep: x f32->bf16 cast; w_qkv, w_proj transpose->bf16 -----------
__global__ __launch_bounds__(256) void k_prep(
    const float* __restrict__ x, unsigned short* __restrict__ xb,
    const float* __restrict__ wqkv, __hip_bfloat16* __restrict__ wqkvT,
    const float* __restrict__ wproj, __hip_bfloat16* __restrict__ wprojT) {
  __shared__ float tile[32][33];
  const int bid = blockIdx.x, tid = threadIdx.x;
  if (bid < 3072) {  // cast: 4096*768 floats, 4/thread
    int i = bid * 256 + tid;
    float4v v = ((const float4v*)x)[i];
    ushort4v o;
#pragma unroll
    for (int r = 0; r < 4; r++) o[r] = f2bf(v[r]);
    ((ushort4v*)xb)[i] = o;
    return;
  }
  const float* w;
  __hip_bfloat16* wt;
  int N, bx, by;
  if (bid < 4800) {
    int t = bid - 3072; w = wqkv; wt = wqkvT; N = 2304; bx = t % 72; by = t / 72;
  } else {
    int t = bid - 4800; w = wproj; wt = wprojT; N = 768; bx = t % 24; by = t / 24;
  }
  const int n0 = bx * 32, k0 = by * 32;
  const int r = tid >> 5, c = tid & 31;
#pragma unroll
  for (int rr = 0; rr < 32; rr += 8)
    tile[rr + r][c] = w[(long long)(k0 + rr + r) * N + n0 + c];
  __syncthreads();
#pragma unroll
  for (int rr = 0; rr < 32; rr += 8)
    wt[(long long)(n0 + rr + r) * 768 + k0 + c] = __float2bfloat16(tile[c][rr + r]);
}

// ---- bf16 GEMM, BK=64, K=768 (12 iters), conflict-free XOR swizzle ---------
// EPI==0: 128x96 tile; scatter Q(prescaled),K->[B,H,S,64] f16, V->VT (+bias).
// EPI==1: 64x64 tile; out f32 [M][768] = acc + bias.
template <int EPI>
__global__ __launch_bounds__(256) void k_gemm_bt(
    const __hip_bfloat16* __restrict__ A, const __hip_bfloat16* __restrict__ Bt,
    const float* __restrict__ bias, float* __restrict__ outF,
    _Float16* __restrict__ Qb, _Float16* __restrict__ Kb,
    _Float16* __restrict__ VT) {
  constexpr int BM = (EPI == 0) ? 128 : 64;
  constexpr int BN = (EPI == 0) ? 96 : 64;
  constexpr int MT = BM / 32;  // 16-tiles per wave (m)
  constexpr int NT = BN / 32;  // 16-tiles per wave (n)
  __shared__ __align__(16) __hip_bfloat16 At[BM * 64];
  __shared__ __align__(16) __hip_bfloat16 Btl[BN * 64];
  const int tid = threadIdx.x;
  const int w = tid >> 6, l = tid & 63;
  const int quad = l >> 4, lane16 = l & 15;
  const int m0 = blockIdx.x * BM, n0 = blockIdx.y * BN;

  float4v acc[MT][NT];
#pragma unroll
  for (int i = 0; i < MT; i++)
#pragma unroll
    for (int j = 0; j < NT; j++) acc[i][j] = float4v{0.f, 0.f, 0.f, 0.f};

  // staging: call c covers rows c*32..c*32+31; thread t -> row c*32+(t>>3),
  // source granule (t&7)^(row&7); dest = base + t*16B
  const int srow = tid >> 3, sgr = tid & 7;
  const __hip_bfloat16* Asrc = A + (long long)(m0 + srow) * 768 + ((sgr ^ (srow & 7)) * 8);
  const __hip_bfloat16* Bsrc = Bt + (long long)(n0 + srow) * 768 + ((sgr ^ (srow & 7)) * 8);
  __hip_bfloat16* Adst = At + tid * 8;
  __hip_bfloat16* Bdst = Btl + tid * 8;

  const int wr = (w >> 1) * (BM / 2), wc = (w & 1) * (BN / 2);
  const int swz = lane16 & 7;

  for (int kt = 0; kt < 12; kt++) {
    const int k0 = kt * 64;
    __syncthreads();
#pragma unroll
    for (int c = 0; c < BM / 32; c++)
      async_copy16(Asrc + (long long)c * 32 * 768 + k0, Adst + c * 2048);
#pragma unroll
    for (int c = 0; c < BN / 32; c++)
      async_copy16(Bsrc + (long long)c * 32 * 768 + k0, Bdst + c * 2048);
    __syncthreads();
#pragma unroll
    for (int h = 0; h < 2; h++) {
      short8 af[MT], bf[NT];
#pragma unroll
      for (int t = 0; t < MT; t++)
        af[t] = *(const short8*)(At + (wr + t * 16 + lane16) * 64 +
                                 (((h * 4 + quad) ^ swz) * 8));
#pragma unroll
      for (int t = 0; t < NT; t++)
        bf[t] = *(const short8*)(Btl + (wc + t * 16 + lane16) * 64 +
                                 (((h * 4 + quad) ^ swz) * 8));
#pragma unroll
      for (int i = 0; i < MT; i++)
#pragma unroll
        for (int j = 0; j < NT; j++)
          acc[i][j] = __builtin_amdgcn_mfma_f32_16x16x32_bf16(af[i], bf[j], acc[i][j], 0, 0, 0);
    }
  }

  // epilogue: C/D layout col=lane16, row=quad*4+reg
#pragma unroll
  for (int i = 0; i < MT; i++) {
    const int mbase = m0 + wr + i * 16 + quad * 4;
#pragma unroll
    for (int j = 0; j < NT; j++) {
      const int n = n0 + wc + j * 16 + lane16;
      const float bv = bias[n];
      if (EPI == 0) {
        const int which = n / 768;  // uniform across the 16-lane tile
        const int rr = n - which * 768;
        const int hh = rr >> 6, dh = rr & 63;
        const float scale = (which == 0) ? LOG2E_8 : 1.0f;
#pragma unroll
        for (int r = 0; r < 4; r++) {
          const int mm = mbase + r;
          const int b = mm >> 11, s = mm & 2047;
          _Float16 val = (_Float16)((acc[i][j][r] + bv) * scale);
          if (which == 0)
            Qb[((long long)(b * 12 + hh) * 2048 + s) * 64 + dh] = val;
          else if (which == 1)
            Kb[((long long)(b * 12 + hh) * 2048 + s) * 64 + dh] = val;
          else
            VT[((long long)(b * 12 + hh) * 64 + dh) * 2048 + s] = val;
        }
      } else {
#pragma unroll
        for (int r = 0; r < 4; r++)
          outF[(long long)(mbase + r) * 768 + n] = acc[i][j][r] + bv;
      }
    }
  }
}

// ---- attention, f16, S^T formulation, 64-key tiles, double-buffered --------
// grid (S/64, B*H), 4 waves; wave = 16 q-rows; ctx written bf16 [4096][768].
// 2-phase schedule: issue next tile's global_load_lds BEFORE computing the
// current tile; one __syncthreads per tile (drains vmcnt -> next buf ready).
__global__ __launch_bounds__(256) void k_attn(
    const _Float16* __restrict__ Qb, const _Float16* __restrict__ Kb,
    const _Float16* __restrict__ VT, unsigned short* __restrict__ ctx) {
  // [buf][key(64)][dh(64)] and [buf][dh(64)][key(64)], 128B rows, 8 granules
  // of 16B, granule slot g holds source granule g^(row&7)  -> conflict-free
  // b128 (K) and b64 (V) fragment reads.
  __shared__ __align__(16) _Float16 Kl[2][64 * 64];
  __shared__ __align__(16) _Float16 Vl[2][64 * 64];
  const int tid = threadIdx.x, w = tid >> 6, l = tid & 63;
  const int quad = l >> 4, lane16 = l & 15;
  const int bh = blockIdx.y;
  const int q0 = blockIdx.x * 64 + w * 16;
  const _Float16* Qp = Qb + (long long)bh * 2048 * 64;
  const _Float16* Kp = Kb + (long long)bh * 2048 * 64;
  const _Float16* Vp = VT + (long long)bh * 64 * 2048;

  // Q as B-frag of S^T: B[n=q=lane16][k=dh=quad*8+j], two k-halves
  half8 qf[2];
#pragma unroll
  for (int hh = 0; hh < 2; hh++)
    qf[hh] = *(const half8*)(Qp + (q0 + lane16) * 64 + hh * 32 + quad * 8);

  float4v o_acc[4];  // O^T[dh=dt*16+quad*4+r][q=lane16]
#pragma unroll
  for (int t = 0; t < 4; t++) o_acc[t] = float4v{0.f, 0.f, 0.f, 0.f};
  float4v sum_acc = float4v{0.f, 0.f, 0.f, 0.f};  // denominator via mfma(ones,P)
  const half4 ones = {(_Float16)1.f, (_Float16)1.f, (_Float16)1.f, (_Float16)1.f};

  // staging: thread t -> row (t>>3)+c*32, granule (t&7)^(row&7); dest linear.
  const int srow = tid >> 3, sg = tid & 7;
  const _Float16* Ksrc = Kp + (long long)srow * 64 + ((sg ^ (srow & 7)) * 8);
  const _Float16* Vsrc = Vp + (long long)srow * 2048 + ((sg ^ (srow & 7)) * 8);
  const int swz = lane16 & 7;

  // prologue: stage tile 0 into buffer 0 (K: 2x4KB calls, V: 2x4KB calls)
#pragma unroll
  for (int c = 0; c < 2; c++) {
    async_copy16(Ksrc + c * 2048, &Kl[0][c * 2048 + tid * 8]);
    async_copy16(Vsrc + (long long)c * 32 * 2048, &Vl[0][c * 2048 + tid * 8]);
  }
  __syncthreads();

  for (int kt = 0; kt < 32; kt++) {
    const int cur = kt & 1;
    if (kt < 31) {  // issue next tile's staging; latency hides under compute
      const long long ko = (long long)(kt + 1) * 4096;  // 64 keys * 64 dh
      const int vo = (kt + 1) * 64;                     // key offset in VT row
#pragma unroll
      for (int c = 0; c < 2; c++) {
        async_copy16(Ksrc + ko + c * 2048, &Kl[cur ^ 1][c * 2048 + tid * 8]);
        async_copy16(Vsrc + vo + (long long)c * 32 * 2048,
                     &Vl[cur ^ 1][c * 2048 + tid * 8]);
      }
    }
    const _Float16* Klc = Kl[cur];
    const _Float16* Vlc = Vl[cur];

    __builtin_amdgcn_s_setprio(1);
    // S^T = K Q^T : A = K-frag [m=key][k=dh]  (Q carries log2e/8)
    float4v s[4];
#pragma unroll
    for (int kb = 0; kb < 4; kb++) {
      const _Float16* kr = Klc + (kb * 16 + lane16) * 64;
      half8 kf0 = *(const half8*)(kr + ((quad ^ swz) * 8));
      half8 kf1 = *(const half8*)(kr + (((4 + quad) ^ swz) * 8));
      float4v z = float4v{0.f, 0.f, 0.f, 0.f};
      z = __builtin_amdgcn_mfma_f32_16x16x32_f16(kf0, qf[0], z, 0, 0, 0);
      s[kb] = __builtin_amdgcn_mfma_f32_16x16x32_f16(kf1, qf[1], z, 0, 0, 0);
    }
    // p = exp2(s'); P^T packed (pk cvt) as K=16 B-frags (k = quad*4 + r)
    half4 pf[4];
#pragma unroll
    for (int kb = 0; kb < 4; kb++) {
      float p0 = fast_exp2(s[kb][0]);
      float p1 = fast_exp2(s[kb][1]);
      float p2 = fast_exp2(s[kb][2]);
      float p3 = fast_exp2(s[kb][3]);
      auto lo = __builtin_amdgcn_cvt_pkrtz(p0, p1);
      auto hi = __builtin_amdgcn_cvt_pkrtz(p2, p3);
      pf[kb] = half4{static_cast<_Float16>(lo[0]), static_cast<_Float16>(lo[1]),
                     static_cast<_Float16>(hi[0]), static_cast<_Float16>(hi[1])};
    }
    // denominator rows (all rows of D identical = sum over the 16 keys)
#pragma unroll
    for (int kb = 0; kb < 4; kb++)
      sum_acc = __builtin_amdgcn_mfma_f32_16x16x16f16(ones, pf[kb], sum_acc, 0, 0, 0);
    // O^T += V^T P^T : A = V-frag [m=dh][k=key]
#pragma unroll
    for (int dt = 0; dt < 4; dt++) {
      const _Float16* vr = Vlc + (dt * 16 + lane16) * 64;
#pragma unroll
      for (int kb = 0; kb < 4; kb++) {
        const int g = kb * 2 + (quad >> 1);
        half4 vf = *(const half4*)(vr + ((g ^ swz) * 8) + (quad & 1) * 4);
        o_acc[dt] = __builtin_amdgcn_mfma_f32_16x16x16f16(vf, pf[kb], o_acc[dt], 0, 0, 0);
      }
    }
    __builtin_amdgcn_s_setprio(0);
    if (kt < 31) __syncthreads();  // drains vmcnt(0): next buffer ready
  }
  // every lane already holds the full denominator for its q=lane16
  const float inv = 1.0f / sum_acc[0];
  const int b = bh / 12, hd = bh - (bh / 12) * 12;
  unsigned short* cp = ctx + ((long long)b * 2048 + q0 + lane16) * 768 + hd * 64 + quad * 4;
#pragma unroll
  for (int dt = 0; dt < 4; dt++) {
    ushort4v cv;
#pragma unroll
    for (int r = 0; r < 4; r++) cv[r] = f2bf(o_acc[dt][r] * inv);
    *(ushort4v*)(cp + dt * 16) = cv;
  }
}

extern "C" void kernel_launch(void* const* d_in, const int* in_sizes, int n_in,
                              void* d_out, int out_size, void* d_ws, size_t ws_size,
                              hipStream_t stream) {
  const float* x = (const float*)d_in[0];
  // d_in[1] attention_mask: masks scaled by +1e-9 -> no-op, dropped
  const float* w_qkv = (const float*)d_in[2];
  const float* b_qkv = (const float*)d_in[3];
  const float* w_proj = (const float*)d_in[4];
  const float* b_proj = (const float*)d_in[5];
  float* out = (float*)d_out;

  char* ws = (char*)d_ws;
  size_t off = 0;
  auto alloc = [&](size_t bytes) {
    void* p = ws + off;
    off += (bytes + 255) & ~(size_t)255;
    return p;
  };
  __hip_bfloat16* Xb = (__hip_bfloat16*)alloc(4096ull * 768 * 2);      // 6.3 MB
  __hip_bfloat16* WqkvT = (__hip_bfloat16*)alloc(2304ull * 768 * 2);   // 3.5 MB
  __hip_bfloat16* WprojT = (__hip_bfloat16*)alloc(768ull * 768 * 2);   // 1.2 MB
  _Float16* Qb = (_Float16*)alloc(3145728ull * 2);                     // 6.3 MB
  _Float16* Kb = (_Float16*)alloc(3145728ull * 2);                     // 6.3 MB
  _Float16* VT = (_Float16*)alloc(3145728ull * 2);                     // 6.3 MB
  __hip_bfloat16* ctx = (__hip_bfloat16*)alloc(4096ull * 768 * 2);     // 6.3 MB

  k_prep<<<5376, 256, 0, stream>>>(x, (unsigned short*)Xb, w_qkv, WqkvT,
                                   w_proj, WprojT);
  k_gemm_bt<0><<<dim3(32, 24), 256, 0, stream>>>(Xb, WqkvT, b_qkv, nullptr,
                                                 Qb, Kb, VT);
  k_attn<<<dim3(32, 24), 256, 0, stream>>>(Qb, Kb, VT, (unsigned short*)ctx);
  k_gemm_bt<1><<<dim3(64, 12), 256, 0, stream>>>(ctx, WprojT, b_proj, out,
                                                 nullptr, nullptr, nullptr);
}

// Round 2
// 152.015 us; speedup vs baseline: 1.0092x; 1.0068x over previous
//
#include <hip/hip_runtime.h>
#include <hip/hip_bf16.h>

// ---------------------------------------------------------------------------
// MultiHeadAttention forward on MI355X (gfx950). B=2,S=2048,D=768,H=12,Dh=64.
// Masks scale by +1e-9 (numeric no-op) -> full non-causal softmax; dropped.
//
// Round 7 = round 6 with the attention pipeline done right (T4):
//  * k_attn: 64-key tiles, TRIPLE-buffered K/V LDS (48 KB, still 3 blocks/CU),
//    prefetch distance 2, raw s_barrier + counted `s_waitcnt vmcnt(4)` (never
//    a full vmem drain in the main loop; round 6's __syncthreads drained
//    vmcnt(0) every tile, which is why it regressed).
//  * k_attn grid XCD-swizzled (T1): each XCD owns 3 heads -> K/V set 1.5 MB
//    fits its 4 MB L2; steady-state loads are L2 hits.
//  * QKV GEMM 128x96 tiles -> (32,24)=768 blocks = 3/CU exact balance.
//  * Proj GEMM 64x64 tiles -> (64,12)=768 blocks = 3/CU.
//  * Prep (f32->bf16 cast + 2 weight transposes) fused into one launch.
// ---------------------------------------------------------------------------

typedef __attribute__((ext_vector_type(8))) short short8;
typedef __attribute__((ext_vector_type(4))) float float4v;
typedef __attribute__((ext_vector_type(8))) _Float16 half8;
typedef __attribute__((ext_vector_type(4))) _Float16 half4;
typedef __attribute__((ext_vector_type(4))) unsigned short ushort4v;

__device__ __forceinline__ void async_copy16(const void* g, void* l) {
  __builtin_amdgcn_global_load_lds(
      (const __attribute__((address_space(1))) void*)g,
      (__attribute__((address_space(3))) void*)l, 16, 0, 0);
}

__device__ __forceinline__ float fast_exp2(float x) {
#if __has_builtin(__builtin_amdgcn_exp2f)
  return __builtin_amdgcn_exp2f(x);
#else
  return exp2f(x);
#endif
}

__device__ __forceinline__ unsigned short f2bf(float v) {
  __hip_bfloat16 h = __float2bfloat16(v);
  unsigned short u;
  __builtin_memcpy(&u, &h, 2);
  return u;
}

#define LOG2E_8 0.18033688011112042f  // log2(e)/8, folded into Q

// ---- fused prep: x f32->bf16 cast; w_qkv, w_proj transpose->bf16 -----------
__global__ __launch_bounds__(256) void k_prep(
    const float* __restrict__ x, unsigned short* __restrict__ xb,
    const float* __restrict__ wqkv, __hip_bfloat16* __restrict__ wqkvT,
    const float* __restrict__ wproj, __hip_bfloat16* __restrict__ wprojT) {
  __shared__ float tile[32][33];
  const int bid = blockIdx.x, tid = threadIdx.x;
  if (bid < 3072) {  // cast: 4096*768 floats, 4/thread
    int i = bid * 256 + tid;
    float4v v = ((const float4v*)x)[i];
    ushort4v o;
#pragma unroll
    for (int r = 0; r < 4; r++) o[r] = f2bf(v[r]);
    ((ushort4v*)xb)[i] = o;
    return;
  }
  const float* w;
  __hip_bfloat16* wt;
  int N, bx, by;
  if (bid < 4800) {
    int t = bid - 3072; w = wqkv; wt = wqkvT; N = 2304; bx = t % 72; by = t / 72;
  } else {
    int t = bid - 4800; w = wproj; wt = wprojT; N = 768; bx = t % 24; by = t / 24;
  }
  const int n0 = bx * 32, k0 = by * 32;
  const int r = tid >> 5, c = tid & 31;
#pragma unroll
  for (int rr = 0; rr < 32; rr += 8)
    tile[rr + r][c] = w[(long long)(k0 + rr + r) * N + n0 + c];
  __syncthreads();
#pragma unroll
  for (int rr = 0; rr < 32; rr += 8)
    wt[(long long)(n0 + rr + r) * 768 + k0 + c] = __float2bfloat16(tile[c][rr + r]);
}

// ---- bf16 GEMM, BK=64, K=768 (12 iters), conflict-free XOR swizzle ---------
// EPI==0: 128x96 tile; scatter Q(prescaled),K->[B,H,S,64] f16, V->VT (+bias).
// EPI==1: 64x64 tile; out f32 [M][768] = acc + bias.
template <int EPI>
__global__ __launch_bounds__(256) void k_gemm_bt(
    const __hip_bfloat16* __restrict__ A, const __hip_bfloat16* __restrict__ Bt,
    const float* __restrict__ bias, float* __restrict__ outF,
    _Float16* __restrict__ Qb, _Float16* __restrict__ Kb,
    _Float16* __restrict__ VT) {
  constexpr int BM = (EPI == 0) ? 128 : 64;
  constexpr int BN = (EPI == 0) ? 96 : 64;
  constexpr int MT = BM / 32;  // 16-tiles per wave (m)
  constexpr int NT = BN / 32;  // 16-tiles per wave (n)
  __shared__ __align__(16) __hip_bfloat16 At[BM * 64];
  __shared__ __align__(16) __hip_bfloat16 Btl[BN * 64];
  const int tid = threadIdx.x;
  const int w = tid >> 6, l = tid & 63;
  const int quad = l >> 4, lane16 = l & 15;
  const int m0 = blockIdx.x * BM, n0 = blockIdx.y * BN;

  float4v acc[MT][NT];
#pragma unroll
  for (int i = 0; i < MT; i++)
#pragma unroll
    for (int j = 0; j < NT; j++) acc[i][j] = float4v{0.f, 0.f, 0.f, 0.f};

  // staging: call c covers rows c*32..c*32+31; thread t -> row c*32+(t>>3),
  // source granule (t&7)^(row&7); dest = base + t*16B
  const int srow = tid >> 3, sgr = tid & 7;
  const __hip_bfloat16* Asrc = A + (long long)(m0 + srow) * 768 + ((sgr ^ (srow & 7)) * 8);
  const __hip_bfloat16* Bsrc = Bt + (long long)(n0 + srow) * 768 + ((sgr ^ (srow & 7)) * 8);
  __hip_bfloat16* Adst = At + tid * 8;
  __hip_bfloat16* Bdst = Btl + tid * 8;

  const int wr = (w >> 1) * (BM / 2), wc = (w & 1) * (BN / 2);
  const int swz = lane16 & 7;

  for (int kt = 0; kt < 12; kt++) {
    const int k0 = kt * 64;
    __syncthreads();
#pragma unroll
    for (int c = 0; c < BM / 32; c++)
      async_copy16(Asrc + (long long)c * 32 * 768 + k0, Adst + c * 2048);
#pragma unroll
    for (int c = 0; c < BN / 32; c++)
      async_copy16(Bsrc + (long long)c * 32 * 768 + k0, Bdst + c * 2048);
    __syncthreads();
#pragma unroll
    for (int h = 0; h < 2; h++) {
      short8 af[MT], bf[NT];
#pragma unroll
      for (int t = 0; t < MT; t++)
        af[t] = *(const short8*)(At + (wr + t * 16 + lane16) * 64 +
                                 (((h * 4 + quad) ^ swz) * 8));
#pragma unroll
      for (int t = 0; t < NT; t++)
        bf[t] = *(const short8*)(Btl + (wc + t * 16 + lane16) * 64 +
                                 (((h * 4 + quad) ^ swz) * 8));
#pragma unroll
      for (int i = 0; i < MT; i++)
#pragma unroll
        for (int j = 0; j < NT; j++)
          acc[i][j] = __builtin_amdgcn_mfma_f32_16x16x32_bf16(af[i], bf[j], acc[i][j], 0, 0, 0);
    }
  }

  // epilogue: C/D layout col=lane16, row=quad*4+reg
#pragma unroll
  for (int i = 0; i < MT; i++) {
    const int mbase = m0 + wr + i * 16 + quad * 4;
#pragma unroll
    for (int j = 0; j < NT; j++) {
      const int n = n0 + wc + j * 16 + lane16;
      const float bv = bias[n];
      if (EPI == 0) {
        const int which = n / 768;  // uniform across the 16-lane tile
        const int rr = n - which * 768;
        const int hh = rr >> 6, dh = rr & 63;
        const float scale = (which == 0) ? LOG2E_8 : 1.0f;
#pragma unroll
        for (int r = 0; r < 4; r++) {
          const int mm = mbase + r;
          const int b = mm >> 11, s = mm & 2047;
          _Float16 val = (_Float16)((acc[i][j][r] + bv) * scale);
          if (which == 0)
            Qb[((long long)(b * 12 + hh) * 2048 + s) * 64 + dh] = val;
          else if (which == 1)
            Kb[((long long)(b * 12 + hh) * 2048 + s) * 64 + dh] = val;
          else
            VT[((long long)(b * 12 + hh) * 64 + dh) * 2048 + s] = val;
        }
      } else {
#pragma unroll
        for (int r = 0; r < 4; r++)
          outF[(long long)(mbase + r) * 768 + n] = acc[i][j][r] + bv;
      }
    }
  }
}

// ---- attention, f16, S^T formulation, 64-key tiles, 3-deep pipeline --------
// grid (S/64, B*H) XCD-swizzled, 4 waves; wave = 16 q-rows.
// Schedule (T3+T4): prefetch distance 2, triple-buffered LDS, one raw
// s_barrier per tile preceded by counted `s_waitcnt vmcnt(4)` -- tile kt's 4
// loads drained, tile kt+1's stay in flight; tile kt+2 issued after barrier.
__global__ __launch_bounds__(256) void k_attn(
    const _Float16* __restrict__ Qb, const _Float16* __restrict__ Kb,
    const _Float16* __restrict__ VT, unsigned short* __restrict__ ctx) {
  // [buf][key(64)][dh(64)] and [buf][dh(64)][key(64)], 128B rows, 8 granules
  // of 16B, granule slot g holds source granule g^(row&7)  -> conflict-free
  // b128 (K) and b64 (V) fragment reads.
  __shared__ __align__(16) _Float16 Kl[3][64 * 64];
  __shared__ __align__(16) _Float16 Vl[3][64 * 64];
  const int tid = threadIdx.x, w = tid >> 6, l = tid & 63;
  const int quad = l >> 4, lane16 = l & 15;

  // XCD swizzle: 768 blocks, 8 XCDs -> each XCD owns 96 consecutive work ids
  // = 3 heads x 32 q-blocks; K/V working set 1.5 MB fits the per-XCD L2.
  const int bid0 = blockIdx.y * 32 + blockIdx.x;
  const int bid = (bid0 & 7) * 96 + (bid0 >> 3);
  const int bh = bid >> 5;
  const int q0 = (bid & 31) * 64 + w * 16;

  const _Float16* Qp = Qb + (long long)bh * 2048 * 64;
  const _Float16* Kp = Kb + (long long)bh * 2048 * 64;
  const _Float16* Vp = VT + (long long)bh * 64 * 2048;

  // Q as B-frag of S^T: B[n=q=lane16][k=dh=quad*8+j], two k-halves
  half8 qf[2];
#pragma unroll
  for (int hh = 0; hh < 2; hh++)
    qf[hh] = *(const half8*)(Qp + (q0 + lane16) * 64 + hh * 32 + quad * 8);

  float4v o_acc[4];  // O^T[dh=dt*16+quad*4+r][q=lane16]
#pragma unroll
  for (int t = 0; t < 4; t++) o_acc[t] = float4v{0.f, 0.f, 0.f, 0.f};
  float4v sum_acc = float4v{0.f, 0.f, 0.f, 0.f};  // denominator via mfma(ones,P)
  const half4 ones = {(_Float16)1.f, (_Float16)1.f, (_Float16)1.f, (_Float16)1.f};

  // staging: thread t -> row (t>>3)+c*32, granule (t&7)^(row&7); dest linear.
  const int srow = tid >> 3, sg = tid & 7;
  const _Float16* Ksrc = Kp + (long long)srow * 64 + ((sg ^ (srow & 7)) * 8);
  const _Float16* Vsrc = Vp + (long long)srow * 2048 + ((sg ^ (srow & 7)) * 8);
  const int swz = lane16 & 7;

  // stage tile t into buffer b: 4 loads/thread, issue order K0,V0,K1,V1
  auto stage = [&](int t, int b) {
    const long long ko = (long long)t * 4096;  // 64 keys * 64 dh
    const int vo = t * 64;                     // key offset in VT row
#pragma unroll
    for (int c = 0; c < 2; c++) {
      async_copy16(Ksrc + ko + c * 2048, &Kl[b][c * 2048 + tid * 8]);
      async_copy16(Vsrc + vo + (long long)c * 32 * 2048, &Vl[b][c * 2048 + tid * 8]);
    }
  };

  auto compute = [&](int b) {
    const _Float16* Klc = Kl[b];
    const _Float16* Vlc = Vl[b];
    __builtin_amdgcn_s_setprio(1);
    // S^T = K Q^T : A = K-frag [m=key][k=dh]  (Q carries log2e/8)
    float4v s[4];
#pragma unroll
    for (int kb = 0; kb < 4; kb++) {
      const _Float16* kr = Klc + (kb * 16 + lane16) * 64;
      half8 kf0 = *(const half8*)(kr + ((quad ^ swz) * 8));
      half8 kf1 = *(const half8*)(kr + (((4 + quad) ^ swz) * 8));
      float4v z = float4v{0.f, 0.f, 0.f, 0.f};
      z = __builtin_amdgcn_mfma_f32_16x16x32_f16(kf0, qf[0], z, 0, 0, 0);
      s[kb] = __builtin_amdgcn_mfma_f32_16x16x32_f16(kf1, qf[1], z, 0, 0, 0);
    }
    // p = exp2(s'); P^T packed (pk cvt) as K=16 B-frags (k = quad*4 + r)
    half4 pf[4];
#pragma unroll
    for (int kb = 0; kb < 4; kb++) {
      float p0 = fast_exp2(s[kb][0]);
      float p1 = fast_exp2(s[kb][1]);
      float p2 = fast_exp2(s[kb][2]);
      float p3 = fast_exp2(s[kb][3]);
      auto lo = __builtin_amdgcn_cvt_pkrtz(p0, p1);
      auto hi = __builtin_amdgcn_cvt_pkrtz(p2, p3);
      pf[kb] = half4{static_cast<_Float16>(lo[0]), static_cast<_Float16>(lo[1]),
                     static_cast<_Float16>(hi[0]), static_cast<_Float16>(hi[1])};
    }
    // denominator rows (all rows of D identical = sum over the 16 keys)
#pragma unroll
    for (int kb = 0; kb < 4; kb++)
      sum_acc = __builtin_amdgcn_mfma_f32_16x16x16f16(ones, pf[kb], sum_acc, 0, 0, 0);
    // O^T += V^T P^T : A = V-frag [m=dh][k=key]
#pragma unroll
    for (int dt = 0; dt < 4; dt++) {
      const _Float16* vr = Vlc + (dt * 16 + lane16) * 64;
#pragma unroll
      for (int kb = 0; kb < 4; kb++) {
        const int g = kb * 2 + (quad >> 1);
        half4 vf = *(const half4*)(vr + ((g ^ swz) * 8) + (quad & 1) * 4);
        o_acc[dt] = __builtin_amdgcn_mfma_f32_16x16x16f16(vf, pf[kb], o_acc[dt], 0, 0, 0);
      }
    }
    __builtin_amdgcn_s_setprio(0);
  };

  // prologue: tiles 0,1 in flight (8 loads)
  stage(0, 0);
  stage(1, 1);

  int cur = 0;
  for (int kt = 0; kt < 31; ++kt) {
    // tile kt's 4 loads done; tile kt+1's 4 may remain in flight
    asm volatile("s_waitcnt vmcnt(4)" ::: "memory");
    __builtin_amdgcn_s_barrier();       // all waves' tile-kt loads landed;
    __builtin_amdgcn_sched_barrier(0);  // nothing crosses the barrier
    if (kt < 30) {
      const int nb = (cur == 0) ? 2 : cur - 1;  // (kt+2)%3
      stage(kt + 2, nb);
    }
    compute(cur);
    cur = (cur == 2) ? 0 : cur + 1;
  }
  asm volatile("s_waitcnt vmcnt(0)" ::: "memory");
  __builtin_amdgcn_s_barrier();
  __builtin_amdgcn_sched_barrier(0);
  compute(cur);

  // every lane already holds the full denominator for its q=lane16
  const float inv = 1.0f / sum_acc[0];
  const int b = bh / 12, hd = bh - (bh / 12) * 12;
  unsigned short* cp = ctx + ((long long)b * 2048 + q0 + lane16) * 768 + hd * 64 + quad * 4;
#pragma unroll
  for (int dt = 0; dt < 4; dt++) {
    ushort4v cv;
#pragma unroll
    for (int r = 0; r < 4; r++) cv[r] = f2bf(o_acc[dt][r] * inv);
    *(ushort4v*)(cp + dt * 16) = cv;
  }
}

extern "C" void kernel_launch(void* const* d_in, const int* in_sizes, int n_in,
                              void* d_out, int out_size, void* d_ws, size_t ws_size,
                              hipStream_t stream) {
  const float* x = (const float*)d_in[0];
  // d_in[1] attention_mask: masks scaled by +1e-9 -> no-op, dropped
  const float* w_qkv = (const float*)d_in[2];
  const float* b_qkv = (const float*)d_in[3];
  const float* w_proj = (const float*)d_in[4];
  const float* b_proj = (const float*)d_in[5];
  float* out = (float*)d_out;

  char* ws = (char*)d_ws;
  size_t off = 0;
  auto alloc = [&](size_t bytes) {
    void* p = ws + off;
    off += (bytes + 255) & ~(size_t)255;
    return p;
  };
  __hip_bfloat16* Xb = (__hip_bfloat16*)alloc(4096ull * 768 * 2);      // 6.3 MB
  __hip_bfloat16* WqkvT = (__hip_bfloat16*)alloc(2304ull * 768 * 2);   // 3.5 MB
  __hip_bfloat16* WprojT = (__hip_bfloat16*)alloc(768ull * 768 * 2);   // 1.2 MB
  _Float16* Qb = (_Float16*)alloc(3145728ull * 2);                     // 6.3 MB
  _Float16* Kb = (_Float16*)alloc(3145728ull * 2);                     // 6.3 MB
  _Float16* VT = (_Float16*)alloc(3145728ull * 2);                     // 6.3 MB
  __hip_bfloat16* ctx = (__hip_bfloat16*)alloc(4096ull * 768 * 2);     // 6.3 MB

  k_prep<<<5376, 256, 0, stream>>>(x, (unsigned short*)Xb, w_qkv, WqkvT,
                                   w_proj, WprojT);
  k_gemm_bt<0><<<dim3(32, 24), 256, 0, stream>>>(Xb, WqkvT, b_qkv, nullptr,
                                                 Qb, Kb, VT);
  k_attn<<<dim3(32, 24), 256, 0, stream>>>(Qb, Kb, VT, (unsigned short*)ctx);
  k_gemm_bt<1><<<dim3(64, 12), 256, 0, stream>>>(ctx, WprojT, b_proj, out,
                                                 nullptr, nullptr, nullptr);
}